// Round 14
// baseline (107.759 us; speedup 1.0000x reference)
//
#include <hip/hip_runtime.h>

// SS2D: B=32,H=32,W=32,DM=128, DIN=64, N=16, R=8, L=1024
// Layouts: xc,u,delta,y = (b,d,l); z = (b,l,d); Bs,Cs = (b,n,l); out = (b,l,dm)

typedef __attribute__((ext_vector_type(8))) short short8;
typedef __attribute__((ext_vector_type(4))) float floatx4;

// split fp32 -> bf16 hi + bf16 lo (truncation; 2-term ~2^-17 rel accuracy)
__device__ __forceinline__ void cvt_split8(const float* v, short8& hi, short8& lo) {
#pragma unroll
    for (int i = 0; i < 8; ++i) {
        const unsigned xb = __float_as_uint(v[i]);
        hi[i] = (short)(xb >> 16);
        const float lf = v[i] - __uint_as_float(xb & 0xFFFF0000u);
        lo[i] = (short)(__float_as_uint(lf) >> 16);
    }
}

// ---------------- K1: xz = x @ w_in^T via dual-bf16 MFMA ---------------------
__global__ __launch_bounds__(256) void k1_gemm_in(
    const float* __restrict__ x, const float* __restrict__ w_in,
    float* __restrict__ xc, float* __restrict__ z)
{
    __shared__ float Cls[64 * 132];
    const int t    = threadIdx.x;
    const int p0   = blockIdx.x * 64;
    const int w    = t >> 6;
    const int l    = t & 63;
    const int lrow = l & 15, lk = l >> 4;
    const int m0   = w * 16;

    floatx4 acc[8];
#pragma unroll
    for (int nt = 0; nt < 8; ++nt) acc[nt] = (floatx4){0.f, 0.f, 0.f, 0.f};

#pragma unroll
    for (int ks = 0; ks < 4; ++ks) {
        const int k0 = ks * 32 + lk * 8;
        float av[8];
        {
            const float* ap = x + (size_t)(p0 + m0 + lrow) * 128 + k0;
            *reinterpret_cast<float4*>(&av[0]) = *reinterpret_cast<const float4*>(ap);
            *reinterpret_cast<float4*>(&av[4]) = *reinterpret_cast<const float4*>(ap + 4);
        }
        short8 ahi, alo;
        cvt_split8(av, ahi, alo);
#pragma unroll
        for (int nt = 0; nt < 8; ++nt) {
            float bv[8];
            const float* bp = w_in + (size_t)(nt * 16 + lrow) * 128 + k0;
            *reinterpret_cast<float4*>(&bv[0]) = *reinterpret_cast<const float4*>(bp);
            *reinterpret_cast<float4*>(&bv[4]) = *reinterpret_cast<const float4*>(bp + 4);
            short8 bhi, blo;
            cvt_split8(bv, bhi, blo);
            acc[nt] = __builtin_amdgcn_mfma_f32_16x16x32_bf16(ahi, bhi, acc[nt], 0, 0, 0);
            acc[nt] = __builtin_amdgcn_mfma_f32_16x16x32_bf16(ahi, blo, acc[nt], 0, 0, 0);
            acc[nt] = __builtin_amdgcn_mfma_f32_16x16x32_bf16(alo, bhi, acc[nt], 0, 0, 0);
        }
    }

#pragma unroll
    for (int nt = 0; nt < 8; ++nt)
#pragma unroll
        for (int r = 0; r < 4; ++r)
            Cls[(m0 + lk * 4 + r) * 132 + nt * 16 + lrow] = acc[nt][r];
    __syncthreads();

    const int b = p0 >> 10, lbase = p0 & 1023;
    {   // xc (b,e,l)
        const int e  = t >> 2;
        const int pg = (t & 3) * 16;
        float tmp[16];
#pragma unroll
        for (int j = 0; j < 16; ++j) tmp[j] = Cls[(pg + j) * 132 + e];
        float* dst = xc + ((size_t)b * 64 + e) * 1024 + lbase + pg;
#pragma unroll
        for (int q = 0; q < 4; ++q)
            *reinterpret_cast<float4*>(dst + q * 4) =
                make_float4(tmp[q*4], tmp[q*4+1], tmp[q*4+2], tmp[q*4+3]);
    }
    {   // z (b,l,d)
        const int pix = t >> 2;
        const int dq  = (t & 3) * 16;
        const float* srcr = &Cls[pix * 132 + 64 + dq];
        float* dst = z + ((size_t)p0 + pix) * 64 + dq;
#pragma unroll
        for (int q = 0; q < 4; ++q)
            *reinterpret_cast<float4*>(dst + q * 4) =
                *reinterpret_cast<const float4*>(srcr + q * 4);
    }
}

// ---------------- K2: depthwise 3x3 conv + bias + SiLU -> u (b,d,l) ----------
__global__ __launch_bounds__(256) void k2_conv(
    const float* __restrict__ xc, const float* __restrict__ cw,
    const float* __restrict__ cb, float* __restrict__ u)
{
    __shared__ float pl[1024];
    const int bd = blockIdx.x;
    const int t  = threadIdx.x;
    const int d  = bd & 63;
    reinterpret_cast<float4*>(pl)[t] =
        reinterpret_cast<const float4*>(xc + (size_t)bd * 1024)[t];
    float w[9];
#pragma unroll
    for (int i = 0; i < 9; ++i) w[i] = cw[d * 9 + i];
    const float bias = cb[d];
    __syncthreads();
    float o[4];
#pragma unroll
    for (int i = 0; i < 4; ++i) {
        const int p  = t * 4 + i;
        const int py = p >> 5, px = p & 31;
        float s = 0.f;
#pragma unroll
        for (int ky = 0; ky < 3; ++ky) {
            const int iy = py + ky - 1;
            if (iy < 0 || iy > 31) continue;
#pragma unroll
            for (int kx = 0; kx < 3; ++kx) {
                const int ix = px + kx - 1;
                if (ix < 0 || ix > 31) continue;
                s = fmaf(pl[iy * 32 + ix], w[ky * 3 + kx], s);
            }
        }
        s += bias;
        o[i] = s / (1.f + __expf(-s));
    }
    reinterpret_cast<float4*>(u + (size_t)bd * 1024)[t] = make_float4(o[0], o[1], o[2], o[3]);
}

// ---------------- K3: x-proj (40 ch) + dt-proj + softplus --------------------
__global__ __launch_bounds__(64) void k3_xproj(
    const float* __restrict__ u, const float* __restrict__ xpw,
    const float* __restrict__ dtw_g, const float* __restrict__ dtb,
    float* __restrict__ delta, float* __restrict__ Bsp, float* __restrict__ Csp)
{
    __shared__ float ut[64][36];   // [d][pix], pad 4
    __shared__ float xw[64 * 40];  // [d][ch]
    __shared__ float xd8[8][36];   // [ch<8][pix]
    __shared__ float dwv[64 * 9];  // [d][r] stride 9
    const int t   = threadIdx.x;
    const int blk = blockIdx.x;
    const int b   = blk >> 5;
    const int l0  = (blk & 31) * 32;

#pragma unroll 4
    for (int c = 0; c < 40; ++c)
        xw[t * 40 + c] = xpw[(size_t)c * 64 + t];
#pragma unroll
    for (int k = 0; k < 8; ++k)
        dwv[t * 9 + k] = dtw_g[t * 8 + k];
    {
        const float* ub = u + (size_t)b * 65536 + l0;
#pragma unroll
        for (int i = t; i < 512; i += 64) {
            const int dd = i >> 3, pq = i & 7;
            const float4 v = *reinterpret_cast<const float4*>(ub + (size_t)dd * 1024 + pq * 4);
            *reinterpret_cast<float4*>(&ut[dd][pq * 4]) = v;
        }
    }
    __syncthreads();

    const int pixq = t & 7;
    const int cg   = t >> 3;
    const int c0   = cg * 5;
    float4 acc[5];
#pragma unroll
    for (int j = 0; j < 5; ++j) acc[j] = make_float4(0.f, 0.f, 0.f, 0.f);
#pragma unroll 8
    for (int dd = 0; dd < 64; ++dd) {
        const float4 uv = *reinterpret_cast<const float4*>(&ut[dd][pixq * 4]);
        const float* row = &xw[dd * 40 + c0];
#pragma unroll
        for (int j = 0; j < 5; ++j) {
            const float w = row[j];
            acc[j].x = fmaf(w, uv.x, acc[j].x);
            acc[j].y = fmaf(w, uv.y, acc[j].y);
            acc[j].z = fmaf(w, uv.z, acc[j].z);
            acc[j].w = fmaf(w, uv.w, acc[j].w);
        }
    }
#pragma unroll
    for (int j = 0; j < 5; ++j) {
        const int c = c0 + j;
        if (c < 8) {
            *reinterpret_cast<float4*>(&xd8[c][pixq * 4]) = acc[j];
        } else if (c < 24) {
            *reinterpret_cast<float4*>(Bsp + (size_t)b * 16384 +
                (size_t)(c - 8) * 1024 + l0 + pixq * 4) = acc[j];
        } else {
            *reinterpret_cast<float4*>(Csp + (size_t)b * 16384 +
                (size_t)(c - 24) * 1024 + l0 + pixq * 4) = acc[j];
        }
    }
    __syncthreads();

    const int dg = t >> 3;
    float dts[4][8];
#pragma unroll
    for (int e = 0; e < 4; ++e)
#pragma unroll
        for (int r = 0; r < 8; ++r)
            dts[e][r] = xd8[r][pixq * 4 + e];
    float* dp = delta + (size_t)b * 65536 + l0 + pixq * 4;
#pragma unroll
    for (int k = 0; k < 8; ++k) {
        const int dd = dg * 8 + k;
        const float* r8 = &dwv[dd * 9];
        const float bias = dtb[dd];
        float ov[4];
#pragma unroll
        for (int e = 0; e < 4; ++e) {
            float s = bias;
#pragma unroll
            for (int r = 0; r < 8; ++r) s = fmaf(dts[e][r], r8[r], s);
            ov[e] = fmaxf(s, 0.f) + log1pf(__expf(-fabsf(s)));
        }
        *reinterpret_cast<float4*>(dp + (size_t)dd * 1024) =
            make_float4(ov[0], ov[1], ov[2], ov[3]);
    }
}

// ---------------- K4: timestep-major chunked scan (block per (b,d)) ----------
// exp values cached in registers across phases (phase C is pure FMA).
__global__ __launch_bounds__(256) void k4_scan(
    const float* __restrict__ delta, const float* __restrict__ u,
    const float* __restrict__ Bsp, const float* __restrict__ Csp,
    const float* __restrict__ A_logs, const float* __restrict__ Ds,
    float* __restrict__ y)
{
    __shared__ float Ps[256][17];
    __shared__ float qs[256][17];
    __shared__ float Sp[16][17];
    __shared__ float Sq[16][17];
    const int t = threadIdx.x;
    const int pair = blockIdx.x;    // b*64 + d
    const int b = pair >> 6, d = pair & 63;

    const float4 d4 = *reinterpret_cast<const float4*>(delta + (size_t)pair * 1024 + t * 4);
    const float4 u4 = *reinterpret_cast<const float4*>(u     + (size_t)pair * 1024 + t * 4);
    const float du0 = d4.x * u4.x, du1 = d4.y * u4.y;
    const float du2 = d4.z * u4.z, du3 = d4.w * u4.w;

    const float* Bb = Bsp + (size_t)b * 16384 + t * 4;
    const float* Cb = Csp + (size_t)b * 16384 + t * 4;

    // ---- phase A: per-state 4-step affine reduce; cache exps in av[] ----
    float av[64];
#pragma unroll
    for (int n = 0; n < 16; ++n) {
        const float Aval = -__expf(A_logs[d * 16 + n]);
        const float4 B4 = *reinterpret_cast<const float4*>(Bb + n * 1024);
        const float a0 = __expf(d4.x * Aval);
        const float a1 = __expf(d4.y * Aval);
        const float a2 = __expf(d4.z * Aval);
        const float a3 = __expf(d4.w * Aval);
        av[4*n+0] = a0; av[4*n+1] = a1; av[4*n+2] = a2; av[4*n+3] = a3;
        float q = du0 * B4.x;
        q = fmaf(a1, q, du1 * B4.y);
        q = fmaf(a2, q, du2 * B4.z);
        q = fmaf(a3, q, du3 * B4.w);
        Ps[t][n] = a0 * a1 * a2 * a3;
        qs[t][n] = q;
    }
    __syncthreads();

    // ---- phase B: scan over 256 chunks (16 segments x 16 chunks) ----
    const int n = t >> 4, g = t & 15;
    float rp[16], rq[16];
    {
        float Pseg = 1.f, qseg = 0.f;
#pragma unroll
        for (int i = 0; i < 16; ++i) {
            const int c = g * 16 + i;
            rp[i] = Ps[c][n]; rq[i] = qs[c][n];
            qseg = fmaf(rp[i], qseg, rq[i]);
            Pseg *= rp[i];
        }
        Sp[g][n] = Pseg; Sq[g][n] = qseg;
    }
    __syncthreads();
    if (t < 16) {
        float h = 0.f;
#pragma unroll
        for (int s = 0; s < 16; ++s) {
            const float Pv = Sp[s][t], qv = Sq[s][t];
            Sp[s][t] = h;
            h = fmaf(Pv, h, qv);
        }
    }
    __syncthreads();
    {
        float h = Sp[g][n];
#pragma unroll
        for (int i = 0; i < 16; ++i) {
            const int c = g * 16 + i;
            qs[c][n] = h;
            h = fmaf(rp[i], h, rq[i]);
        }
    }
    __syncthreads();

    // ---- phase C: replay with cached exps (no trans ops) ----
    const float Dval = Ds[d];
    float y0 = Dval * u4.x, y1 = Dval * u4.y, y2 = Dval * u4.z, y3 = Dval * u4.w;
#pragma unroll
    for (int nn = 0; nn < 16; ++nn) {
        const float4 B4 = *reinterpret_cast<const float4*>(Bb + nn * 1024);
        const float4 C4 = *reinterpret_cast<const float4*>(Cb + nn * 1024);
        float h = qs[t][nn];
        h = fmaf(av[4*nn+0], h, du0 * B4.x); y0 = fmaf(h, C4.x, y0);
        h = fmaf(av[4*nn+1], h, du1 * B4.y); y1 = fmaf(h, C4.y, y1);
        h = fmaf(av[4*nn+2], h, du2 * B4.z); y2 = fmaf(h, C4.z, y2);
        h = fmaf(av[4*nn+3], h, du3 * B4.w); y3 = fmaf(h, C4.w, y3);
    }
    *reinterpret_cast<float4*>(y + (size_t)pair * 1024 + t * 4) =
        make_float4(y0, y1, y2, y3);
}

// ---------------- K5: LayerNorm + silu(z) gate + MFMA out GEMM ---------------
__global__ __launch_bounds__(256) void k5_out(
    const float* __restrict__ y, const float* __restrict__ z,
    const float* __restrict__ ln_g, const float* __restrict__ ln_b,
    const float* __restrict__ w_out, float* __restrict__ out)
{
    __shared__ float yn[64 * 68];   // [l_local][d] stride 68
    __shared__ float Cls[64 * 132]; // epilogue bounce
    const int t  = threadIdx.x;
    const int p0 = blockIdx.x * 64;
    const int b  = p0 >> 10, l0 = p0 & 1023;

    // transpose-load y tile (b,d,l) -> yn[l][d]
    {
        const int d = t >> 2;
        const float* yrow = y + ((size_t)b * 64 + d) * 1024 + l0;
#pragma unroll
        for (int k = 0; k < 4; ++k) {
            const int c4 = ((t & 3) + k * 4) * 4;
            const float4 v = *reinterpret_cast<const float4*>(&yrow[c4]);
            yn[(c4 + 0) * 68 + d] = v.x;
            yn[(c4 + 1) * 68 + d] = v.y;
            yn[(c4 + 2) * 68 + d] = v.z;
            yn[(c4 + 3) * 68 + d] = v.w;
        }
    }
    __syncthreads();

    const int lane = t & 63, wv = t >> 6;
    const float g = ln_g[lane], bbv = ln_b[lane];
#pragma unroll 1
    for (int i = 0; i < 16; ++i) {
        const int pl = wv * 16 + i;
        const size_t p = (size_t)p0 + pl;
        const float v  = yn[pl * 68 + lane];
        const float zv = z[p * 64 + lane];
        float s1 = v, s2 = v * v;
#pragma unroll
        for (int m = 1; m < 64; m <<= 1) {
            s1 += __shfl_xor(s1, m);
            s2 += __shfl_xor(s2, m);
        }
        const float mu   = s1 * (1.f / 64.f);
        const float var  = s2 * (1.f / 64.f) - mu * mu;
        const float rstd = rsqrtf(var + 1e-5f);
        const float sz   = zv / (1.f + __expf(-zv));
        yn[pl * 68 + lane] = ((v - mu) * rstd * g + bbv) * sz;
    }
    __syncthreads();

    // MFMA GEMM: C[64 pix][128 dm] = yn[64][64] @ w_out^T (K=64)
    const int lrow = lane & 15, lk = lane >> 4;
    const int m0   = wv * 16;
    floatx4 acc[8];
#pragma unroll
    for (int nt = 0; nt < 8; ++nt) acc[nt] = (floatx4){0.f, 0.f, 0.f, 0.f};

#pragma unroll
    for (int ks = 0; ks < 2; ++ks) {
        const int k0 = ks * 32 + lk * 8;
        float av[8];
        {
            const float* ap = &yn[(m0 + lrow) * 68 + k0];
            *reinterpret_cast<float4*>(&av[0]) = *reinterpret_cast<const float4*>(ap);
            *reinterpret_cast<float4*>(&av[4]) = *reinterpret_cast<const float4*>(ap + 4);
        }
        short8 ahi, alo;
        cvt_split8(av, ahi, alo);
#pragma unroll
        for (int nt = 0; nt < 8; ++nt) {
            float bv[8];
            const float* bp = w_out + (size_t)(nt * 16 + lrow) * 64 + k0;
            *reinterpret_cast<float4*>(&bv[0]) = *reinterpret_cast<const float4*>(bp);
            *reinterpret_cast<float4*>(&bv[4]) = *reinterpret_cast<const float4*>(bp + 4);
            short8 bhi, blo;
            cvt_split8(bv, bhi, blo);
            acc[nt] = __builtin_amdgcn_mfma_f32_16x16x32_bf16(ahi, bhi, acc[nt], 0, 0, 0);
            acc[nt] = __builtin_amdgcn_mfma_f32_16x16x32_bf16(ahi, blo, acc[nt], 0, 0, 0);
            acc[nt] = __builtin_amdgcn_mfma_f32_16x16x32_bf16(alo, bhi, acc[nt], 0, 0, 0);
        }
    }

#pragma unroll
    for (int nt = 0; nt < 8; ++nt)
#pragma unroll
        for (int r = 0; r < 4; ++r)
            Cls[(m0 + lk * 4 + r) * 132 + nt * 16 + lrow] = acc[nt][r];
    __syncthreads();

    {   // coalesced out store: thread = (pix = t>>2, 32-dm group)
        const int pix = t >> 2;
        const int dq  = (t & 3) * 32;
        const float* srcr = &Cls[pix * 132 + dq];
        float* dst = out + ((size_t)p0 + pix) * 128 + dq;
#pragma unroll
        for (int q = 0; q < 8; ++q)
            *reinterpret_cast<float4*>(dst + q * 4) =
                *reinterpret_cast<const float4*>(srcr + q * 4);
    }
}

extern "C" void kernel_launch(void* const* d_in, const int* in_sizes, int n_in,
                              void* d_out, int out_size, void* d_ws, size_t ws_size,
                              hipStream_t stream)
{
    const float* x        = (const float*)d_in[0];
    const float* w_in     = (const float*)d_in[1];
    const float* conv_w   = (const float*)d_in[2];
    const float* conv_b   = (const float*)d_in[3];
    const float* xproj_w  = (const float*)d_in[4];
    const float* dtproj_w = (const float*)d_in[5];
    const float* dtproj_b = (const float*)d_in[6];
    const float* A_logs   = (const float*)d_in[7];
    const float* Ds       = (const float*)d_in[8];
    const float* ln_g     = (const float*)d_in[9];
    const float* ln_b     = (const float*)d_in[10];
    const float* w_out    = (const float*)d_in[11];
    float* out = (float*)d_out;
    float* ws  = (float*)d_ws;

    const size_t M  = (size_t)2097152;  // 32*64*1024
    float* xc    = ws;                  // 8 MB
    float* z     = ws + M;              // 8 MB
    float* u     = ws + 2 * M;          // 8 MB
    float* delta = ws + 3 * M;          // 8 MB
    float* y     = ws + 4 * M;          // 8 MB  (b,d,l)
    float* Bsp   = ws + 5 * M;          // 2 MB
    float* Csp   = Bsp + 524288;        // 2 MB

    k1_gemm_in<<<512, 256, 0, stream>>>(x, w_in, xc, z);
    k2_conv<<<2048, 256, 0, stream>>>(xc, conv_w, conv_b, u);
    k3_xproj<<<1024, 64, 0, stream>>>(u, xproj_w, dtproj_w, dtproj_b, delta, Bsp, Csp);
    k4_scan<<<2048, 256, 0, stream>>>(delta, u, Bsp, Csp, A_logs, Ds, y);
    k5_out<<<512, 256, 0, stream>>>(y, z, ln_g, ln_b, w_out, out);
}

// Round 15
// 100.605 us; speedup vs baseline: 1.0711x; 1.0711x over previous
//
#include <hip/hip_runtime.h>

// SS2D: B=32,H=32,W=32,DM=128, DIN=64, N=16, R=8, L=1024
// Layouts: xc,u,delta,y = (b,d,l); z = (b,l,d); Bs,Cs = (b,n,l); out = (b,l,dm)

// ---------------- K1: xz = x @ w_in^T ; split into xc (NCHW) and z (b,l,d) ----
__global__ __launch_bounds__(256) void k1_gemm_in(
    const float* __restrict__ x, const float* __restrict__ w_in,
    float* __restrict__ xc, float* __restrict__ z)
{
    __shared__ float As[32 * 68];    // [k][m], stride 68
    __shared__ float Ws[32 * 132];   // [k][e], stride 132
    const int t  = threadIdx.x;
    const int p0 = blockIdx.x * 64;
    const int tx = t & 15, ty = t >> 4;

    float acc[4][8];
#pragma unroll
    for (int i = 0; i < 4; ++i)
#pragma unroll
        for (int j = 0; j < 8; ++j) acc[i][j] = 0.f;

    for (int kk = 0; kk < 128; kk += 32) {
        {
            const int m  = t >> 3;
            const int c4 = (t & 7) * 4;
            const float4 v0 = *reinterpret_cast<const float4*>(&x[(size_t)(p0 + m) * 128 + kk + c4]);
            const float4 v1 = *reinterpret_cast<const float4*>(&x[(size_t)(p0 + m + 32) * 128 + kk + c4]);
            As[(c4 + 0) * 68 + m] = v0.x; As[(c4 + 1) * 68 + m] = v0.y;
            As[(c4 + 2) * 68 + m] = v0.z; As[(c4 + 3) * 68 + m] = v0.w;
            As[(c4 + 0) * 68 + m + 32] = v1.x; As[(c4 + 1) * 68 + m + 32] = v1.y;
            As[(c4 + 2) * 68 + m + 32] = v1.z; As[(c4 + 3) * 68 + m + 32] = v1.w;
        }
        for (int i = t; i < 4096; i += 256) {
            const int c = i & 31, e = i >> 5;
            Ws[c * 132 + e] = w_in[(size_t)e * 128 + kk + c];
        }
        __syncthreads();
#pragma unroll
        for (int k = 0; k < 32; ++k) {
            const float4 a  = *reinterpret_cast<const float4*>(&As[k * 68 + (ty << 2)]);
            const float4 b0 = *reinterpret_cast<const float4*>(&Ws[k * 132 + (tx << 3)]);
            const float4 b1 = *reinterpret_cast<const float4*>(&Ws[k * 132 + (tx << 3) + 4]);
            const float am[4] = {a.x, a.y, a.z, a.w};
            const float bm[8] = {b0.x, b0.y, b0.z, b0.w, b1.x, b1.y, b1.z, b1.w};
#pragma unroll
            for (int i = 0; i < 4; ++i)
#pragma unroll
                for (int j = 0; j < 8; ++j)
                    acc[i][j] = fmaf(am[i], bm[j], acc[i][j]);
        }
        __syncthreads();
    }

    const int b  = p0 >> 10;
    const int l0 = (p0 & 1023) + (ty << 2);
    if (tx < 8) {
#pragma unroll
        for (int j = 0; j < 8; ++j) {
            const int e = (tx << 3) + j;
            *reinterpret_cast<float4*>(&xc[((size_t)b * 64 + e) * 1024 + l0]) =
                make_float4(acc[0][j], acc[1][j], acc[2][j], acc[3][j]);
        }
    } else {
        const int d0 = (tx - 8) << 3;
#pragma unroll
        for (int i = 0; i < 4; ++i) {
            const size_t p = (size_t)p0 + (ty << 2) + i;
            *reinterpret_cast<float4*>(&z[p * 64 + d0]) =
                make_float4(acc[i][0], acc[i][1], acc[i][2], acc[i][3]);
            *reinterpret_cast<float4*>(&z[p * 64 + d0 + 4]) =
                make_float4(acc[i][4], acc[i][5], acc[i][6], acc[i][7]);
        }
    }
}

// ---------------- K23: fused depthwise conv + SiLU + x-proj + dt-proj --------
// 512 blocks x 256 threads; block = (b, strip s of 2 image rows = 64 pixels).
// Stage xc rows [2s-1, 2s+2] (zero-padded) -> conv+SiLU -> ut + u store ->
// x-proj from ut -> Bs/Cs direct stores, ch 0..7 -> xd8 -> dt-proj+softplus.
__global__ __launch_bounds__(256) void k23_conv_xproj(
    const float* __restrict__ xc, const float* __restrict__ cw,
    const float* __restrict__ cb, const float* __restrict__ xpw,
    const float* __restrict__ dtw_g, const float* __restrict__ dtb,
    float* __restrict__ u, float* __restrict__ delta,
    float* __restrict__ Bsp, float* __restrict__ Csp)
{
    __shared__ float xct[64][132];  // [d][4 rows x 32 cols]
    __shared__ float ut[64][68];    // [d][pix 0..63]
    __shared__ float xw[64 * 40];   // [d][ch]
    __shared__ float xd8[8][68];    // [ch<8][pix]
    __shared__ float wls[64][10];   // conv weights
    __shared__ float cbl[64];
    __shared__ float dwv[64 * 9];   // dt weights, stride 9

    const int t   = threadIdx.x;
    const int blk = blockIdx.x;     // 512
    const int b   = blk >> 4;
    const int s   = blk & 15;
    const int l0  = s * 64;

    for (int i = t; i < 576; i += 256) wls[i / 9][i % 9] = cw[i];
    if (t < 64) cbl[t] = cb[t];
    for (int i = t; i < 2560; i += 256) {
        const int dd = i / 40, c = i - dd * 40;
        xw[dd * 40 + c] = xpw[(size_t)c * 64 + dd];
    }
    for (int i = t; i < 512; i += 256) dwv[(i >> 3) * 9 + (i & 7)] = dtw_g[i];

    // stage xct: 128 contiguous floats per d (rows 2s-1..2s+2), coalesced,
    // zero-padded at image edges. thread t: d = t>>2, owns float4s q,q+4,...
    {
        const int d = t >> 2, q = t & 3;
        const float* src = xc + ((size_t)b * 64 + d) * 1024 + (2 * s - 1) * 32;
        float* dst = &xct[d][0];
#pragma unroll
        for (int k = 0; k < 8; ++k) {
            const int j  = k * 4 + q;          // float4 index in [0,32)
            const int rr = 2 * s - 1 + (j >> 3);
            float4 v = make_float4(0.f, 0.f, 0.f, 0.f);
            if (rr >= 0 && rr < 32)
                v = *reinterpret_cast<const float4*>(src + j * 4);
            *reinterpret_cast<float4*>(dst + j * 4) = v;
        }
    }
    __syncthreads();

    // conv + bias + SiLU -> ut[d][p] and u (coalesced 64-float rows)
    {
        const int p  = t & 63;
        const int py = p >> 5, px = p & 31;
        const int dg = t >> 6;
#pragma unroll
        for (int kd = 0; kd < 16; ++kd) {
            const int d = dg * 16 + kd;
            float sacc = cbl[d];
#pragma unroll
            for (int ky = 0; ky < 3; ++ky) {
#pragma unroll
                for (int kx = 0; kx < 3; ++kx) {
                    const int xx = px + kx - 1;
                    if (xx >= 0 && xx < 32)
                        sacc = fmaf(xct[d][(py + ky) * 32 + xx],
                                    wls[d][ky * 3 + kx], sacc);
                }
            }
            const float uv = sacc / (1.f + __expf(-sacc));
            ut[d][p] = uv;
            u[((size_t)b * 64 + d) * 1024 + l0 + p] = uv;
        }
    }
    __syncthreads();

    // x-proj: thread = (p2 = (t&31)*2 -> 2 pixels, cg = t>>5 -> 5 channels)
    {
        const int p2 = (t & 31) * 2;
        const int c0 = (t >> 5) * 5;
        float2 acc[5];
#pragma unroll
        for (int j = 0; j < 5; ++j) acc[j] = make_float2(0.f, 0.f);
#pragma unroll 8
        for (int dd = 0; dd < 64; ++dd) {
            const float2 uv = *reinterpret_cast<const float2*>(&ut[dd][p2]);
            const float* row = &xw[dd * 40 + c0];
#pragma unroll
            for (int j = 0; j < 5; ++j) {
                acc[j].x = fmaf(row[j], uv.x, acc[j].x);
                acc[j].y = fmaf(row[j], uv.y, acc[j].y);
            }
        }
#pragma unroll
        for (int j = 0; j < 5; ++j) {
            const int c = c0 + j;
            if (c < 8) {
                *reinterpret_cast<float2*>(&xd8[c][p2]) = acc[j];
            } else if (c < 24) {
                *reinterpret_cast<float2*>(Bsp + (size_t)b * 16384 +
                    (size_t)(c - 8) * 1024 + l0 + p2) = acc[j];
            } else {
                *reinterpret_cast<float2*>(Csp + (size_t)b * 16384 +
                    (size_t)(c - 24) * 1024 + l0 + p2) = acc[j];
            }
        }
    }
    __syncthreads();

    // dt-proj + softplus: thread = (p = t&63, dg = t>>6 -> 16 d's)
    {
        const int p  = t & 63;
        const int dg = t >> 6;
        float dts[8];
#pragma unroll
        for (int r = 0; r < 8; ++r) dts[r] = xd8[r][p];
        float* dp = delta + (size_t)b * 65536 + l0 + p;
#pragma unroll
        for (int kd = 0; kd < 16; ++kd) {
            const int dd = dg * 16 + kd;
            const float* r8 = &dwv[dd * 9];
            float sv = dtb[dd];
#pragma unroll
            for (int r = 0; r < 8; ++r) sv = fmaf(dts[r], r8[r], sv);
            dp[(size_t)dd * 1024] = fmaxf(sv, 0.f) + log1pf(__expf(-fabsf(sv)));
        }
    }
}

// ---------------- K4: timestep-major chunked scan (block per (b,d)) ----------
__global__ __launch_bounds__(256) void k4_scan(
    const float* __restrict__ delta, const float* __restrict__ u,
    const float* __restrict__ Bsp, const float* __restrict__ Csp,
    const float* __restrict__ A_logs, const float* __restrict__ Ds,
    float* __restrict__ y)
{
    __shared__ float Ps[256][17];
    __shared__ float qs[256][17];
    __shared__ float Sp[16][17];
    __shared__ float Sq[16][17];
    const int t = threadIdx.x;
    const int pair = blockIdx.x;    // b*64 + d
    const int b = pair >> 6, d = pair & 63;

    float A[16];
#pragma unroll
    for (int n = 0; n < 16; ++n) A[n] = -__expf(A_logs[d * 16 + n]);

    const float4 d4 = *reinterpret_cast<const float4*>(delta + (size_t)pair * 1024 + t * 4);
    const float4 u4 = *reinterpret_cast<const float4*>(u     + (size_t)pair * 1024 + t * 4);
    const float du0 = d4.x * u4.x, du1 = d4.y * u4.y;
    const float du2 = d4.z * u4.z, du3 = d4.w * u4.w;

    const float* Bb = Bsp + (size_t)b * 16384 + t * 4;
    const float* Cb = Csp + (size_t)b * 16384 + t * 4;

    // ---- phase A ----
#pragma unroll
    for (int n = 0; n < 16; ++n) {
        const float4 B4 = *reinterpret_cast<const float4*>(Bb + n * 1024);
        float a, P, q;
        a = __expf(d4.x * A[n]); P = a;   q = du0 * B4.x;
        a = __expf(d4.y * A[n]); P *= a;  q = fmaf(a, q, du1 * B4.y);
        a = __expf(d4.z * A[n]); P *= a;  q = fmaf(a, q, du2 * B4.z);
        a = __expf(d4.w * A[n]); P *= a;  q = fmaf(a, q, du3 * B4.w);
        Ps[t][n] = P; qs[t][n] = q;
    }
    __syncthreads();

    // ---- phase B ----
    const int n = t >> 4, g = t & 15;
    float rp[16], rq[16];
    {
        float Pseg = 1.f, qseg = 0.f;
#pragma unroll
        for (int i = 0; i < 16; ++i) {
            const int c = g * 16 + i;
            rp[i] = Ps[c][n]; rq[i] = qs[c][n];
            qseg = fmaf(rp[i], qseg, rq[i]);
            Pseg *= rp[i];
        }
        Sp[g][n] = Pseg; Sq[g][n] = qseg;
    }
    __syncthreads();
    if (t < 16) {
        float h = 0.f;
#pragma unroll
        for (int s = 0; s < 16; ++s) {
            const float Pv = Sp[s][t], qv = Sq[s][t];
            Sp[s][t] = h;
            h = fmaf(Pv, h, qv);
        }
    }
    __syncthreads();
    {
        float h = Sp[g][n];
#pragma unroll
        for (int i = 0; i < 16; ++i) {
            const int c = g * 16 + i;
            qs[c][n] = h;
            h = fmaf(rp[i], h, rq[i]);
        }
    }
    __syncthreads();

    // ---- phase C ----
    const float Dval = Ds[d];
    float y0 = Dval * u4.x, y1 = Dval * u4.y, y2 = Dval * u4.z, y3 = Dval * u4.w;
#pragma unroll
    for (int nn = 0; nn < 16; ++nn) {
        const float4 B4 = *reinterpret_cast<const float4*>(Bb + nn * 1024);
        const float4 C4 = *reinterpret_cast<const float4*>(Cb + nn * 1024);
        float h = qs[t][nn];
        float a;
        a = __expf(d4.x * A[nn]); h = fmaf(a, h, du0 * B4.x); y0 = fmaf(h, C4.x, y0);
        a = __expf(d4.y * A[nn]); h = fmaf(a, h, du1 * B4.y); y1 = fmaf(h, C4.y, y1);
        a = __expf(d4.z * A[nn]); h = fmaf(a, h, du2 * B4.z); y2 = fmaf(h, C4.z, y2);
        a = __expf(d4.w * A[nn]); h = fmaf(a, h, du3 * B4.w); y3 = fmaf(h, C4.w, y3);
    }
    *reinterpret_cast<float4*>(y + (size_t)pair * 1024 + t * 4) =
        make_float4(y0, y1, y2, y3);
}

// ---------------- K5: LayerNorm + silu(z) gate + out GEMM --------------------
__global__ __launch_bounds__(256) void k5_out(
    const float* __restrict__ y, const float* __restrict__ z,
    const float* __restrict__ ln_g, const float* __restrict__ ln_b,
    const float* __restrict__ w_out, float* __restrict__ out)
{
    __shared__ float yn[64 * 68];   // [l_local][d] stride 68
    __shared__ float wo[64 * 132];  // [d][c] pad 132
    const int t  = threadIdx.x;
    const int p0 = blockIdx.x * 64;
    const int b  = p0 >> 10, l0 = p0 & 1023;

    for (int i = t; i < 8192; i += 256) {
        const int c = i >> 6, dd = i & 63;
        wo[dd * 132 + c] = w_out[i];
    }

    {
        const int d = t >> 2;
        const float* yrow = y + ((size_t)b * 64 + d) * 1024 + l0;
#pragma unroll
        for (int k = 0; k < 4; ++k) {
            const int c4 = ((t & 3) + k * 4) * 4;
            const float4 v = *reinterpret_cast<const float4*>(&yrow[c4]);
            yn[(c4 + 0) * 68 + d] = v.x;
            yn[(c4 + 1) * 68 + d] = v.y;
            yn[(c4 + 2) * 68 + d] = v.z;
            yn[(c4 + 3) * 68 + d] = v.w;
        }
    }
    __syncthreads();

    const int lane = t & 63, wv = t >> 6;
    const float g = ln_g[lane], bbv = ln_b[lane];
#pragma unroll 1
    for (int i = 0; i < 16; ++i) {
        const int pl = wv * 16 + i;
        const size_t p = (size_t)p0 + pl;
        const float v  = yn[pl * 68 + lane];
        const float zv = z[p * 64 + lane];
        float s1 = v, s2 = v * v;
#pragma unroll
        for (int m = 1; m < 64; m <<= 1) {
            s1 += __shfl_xor(s1, m);
            s2 += __shfl_xor(s2, m);
        }
        const float mu   = s1 * (1.f / 64.f);
        const float var  = s2 * (1.f / 64.f) - mu * mu;
        const float rstd = rsqrtf(var + 1e-5f);
        const float sz   = zv / (1.f + __expf(-zv));
        yn[pl * 68 + lane] = ((v - mu) * rstd * g + bbv) * sz;
    }
    __syncthreads();

    const int tx = t & 31, ty = t >> 5;
    float acc[8][4];
#pragma unroll
    for (int i = 0; i < 8; ++i)
#pragma unroll
        for (int j = 0; j < 4; ++j) acc[i][j] = 0.f;

    for (int dd = 0; dd < 64; ++dd) {
        const float4 w4 = *reinterpret_cast<const float4*>(&wo[dd * 132 + (tx << 2)]);
#pragma unroll
        for (int i = 0; i < 8; ++i) {
            const float a = yn[(ty * 8 + i) * 68 + dd];
            acc[i][0] = fmaf(a, w4.x, acc[i][0]);
            acc[i][1] = fmaf(a, w4.y, acc[i][1]);
            acc[i][2] = fmaf(a, w4.z, acc[i][2]);
            acc[i][3] = fmaf(a, w4.w, acc[i][3]);
        }
    }
#pragma unroll
    for (int i = 0; i < 8; ++i) {
        const size_t p = (size_t)p0 + ty * 8 + i;
        *reinterpret_cast<float4*>(&out[p * 128 + (tx << 2)]) =
            make_float4(acc[i][0], acc[i][1], acc[i][2], acc[i][3]);
    }
}

extern "C" void kernel_launch(void* const* d_in, const int* in_sizes, int n_in,
                              void* d_out, int out_size, void* d_ws, size_t ws_size,
                              hipStream_t stream)
{
    const float* x        = (const float*)d_in[0];
    const float* w_in     = (const float*)d_in[1];
    const float* conv_w   = (const float*)d_in[2];
    const float* conv_b   = (const float*)d_in[3];
    const float* xproj_w  = (const float*)d_in[4];
    const float* dtproj_w = (const float*)d_in[5];
    const float* dtproj_b = (const float*)d_in[6];
    const float* A_logs   = (const float*)d_in[7];
    const float* Ds       = (const float*)d_in[8];
    const float* ln_g     = (const float*)d_in[9];
    const float* ln_b     = (const float*)d_in[10];
    const float* w_out    = (const float*)d_in[11];
    float* out = (float*)d_out;
    float* ws  = (float*)d_ws;

    const size_t M  = (size_t)2097152;  // 32*64*1024
    float* xc    = ws;                  // 8 MB
    float* z     = ws + M;              // 8 MB
    float* u     = ws + 2 * M;          // 8 MB
    float* delta = ws + 3 * M;          // 8 MB
    float* y     = ws + 4 * M;          // 8 MB  (b,d,l)
    float* Bsp   = ws + 5 * M;          // 2 MB
    float* Csp   = Bsp + 524288;        // 2 MB

    k1_gemm_in<<<512, 256, 0, stream>>>(x, w_in, xc, z);
    k23_conv_xproj<<<512, 256, 0, stream>>>(xc, conv_w, conv_b, xproj_w,
                                            dtproj_w, dtproj_b, u, delta, Bsp, Csp);
    k4_scan<<<2048, 256, 0, stream>>>(delta, u, Bsp, Csp, A_logs, Ds, y);
    k5_out<<<512, 256, 0, stream>>>(y, z, ln_g, ln_b, w_out, out);
}

// Round 16
// 95.318 us; speedup vs baseline: 1.1305x; 1.0555x over previous
//
#include <hip/hip_runtime.h>

// SS2D: B=32,H=32,W=32,DM=128, DIN=64, N=16, R=8, L=1024
// Layouts: xc,u,delta,y = (b,d,l); z = (b,l,d); Bs,Cs = (b,n,l); out = (b,l,dm)

// ---------------- K1: xz = x @ w_in^T ; split into xc (NCHW) and z (b,l,d) ----
__global__ __launch_bounds__(256) void k1_gemm_in(
    const float* __restrict__ x, const float* __restrict__ w_in,
    float* __restrict__ xc, float* __restrict__ z)
{
    __shared__ float As[32 * 68];    // [k][m], stride 68
    __shared__ float Ws[32 * 132];   // [k][e], stride 132
    const int t  = threadIdx.x;
    const int p0 = blockIdx.x * 64;
    const int tx = t & 15, ty = t >> 4;

    float acc[4][8];
#pragma unroll
    for (int i = 0; i < 4; ++i)
#pragma unroll
        for (int j = 0; j < 8; ++j) acc[i][j] = 0.f;

    for (int kk = 0; kk < 128; kk += 32) {
        {
            const int m  = t >> 3;
            const int c4 = (t & 7) * 4;
            const float4 v0 = *reinterpret_cast<const float4*>(&x[(size_t)(p0 + m) * 128 + kk + c4]);
            const float4 v1 = *reinterpret_cast<const float4*>(&x[(size_t)(p0 + m + 32) * 128 + kk + c4]);
            As[(c4 + 0) * 68 + m] = v0.x; As[(c4 + 1) * 68 + m] = v0.y;
            As[(c4 + 2) * 68 + m] = v0.z; As[(c4 + 3) * 68 + m] = v0.w;
            As[(c4 + 0) * 68 + m + 32] = v1.x; As[(c4 + 1) * 68 + m + 32] = v1.y;
            As[(c4 + 2) * 68 + m + 32] = v1.z; As[(c4 + 3) * 68 + m + 32] = v1.w;
        }
        for (int i = t; i < 4096; i += 256) {
            const int c = i & 31, e = i >> 5;
            Ws[c * 132 + e] = w_in[(size_t)e * 128 + kk + c];
        }
        __syncthreads();
#pragma unroll
        for (int k = 0; k < 32; ++k) {
            const float4 a  = *reinterpret_cast<const float4*>(&As[k * 68 + (ty << 2)]);
            const float4 b0 = *reinterpret_cast<const float4*>(&Ws[k * 132 + (tx << 3)]);
            const float4 b1 = *reinterpret_cast<const float4*>(&Ws[k * 132 + (tx << 3) + 4]);
            const float am[4] = {a.x, a.y, a.z, a.w};
            const float bm[8] = {b0.x, b0.y, b0.z, b0.w, b1.x, b1.y, b1.z, b1.w};
#pragma unroll
            for (int i = 0; i < 4; ++i)
#pragma unroll
                for (int j = 0; j < 8; ++j)
                    acc[i][j] = fmaf(am[i], bm[j], acc[i][j]);
        }
        __syncthreads();
    }

    const int b  = p0 >> 10;
    const int l0 = (p0 & 1023) + (ty << 2);
    if (tx < 8) {
#pragma unroll
        for (int j = 0; j < 8; ++j) {
            const int e = (tx << 3) + j;
            *reinterpret_cast<float4*>(&xc[((size_t)b * 64 + e) * 1024 + l0]) =
                make_float4(acc[0][j], acc[1][j], acc[2][j], acc[3][j]);
        }
    } else {
        const int d0 = (tx - 8) << 3;
#pragma unroll
        for (int i = 0; i < 4; ++i) {
            const size_t p = (size_t)p0 + (ty << 2) + i;
            *reinterpret_cast<float4*>(&z[p * 64 + d0]) =
                make_float4(acc[i][0], acc[i][1], acc[i][2], acc[i][3]);
            *reinterpret_cast<float4*>(&z[p * 64 + d0 + 4]) =
                make_float4(acc[i][4], acc[i][5], acc[i][6], acc[i][7]);
        }
    }
}

// ---------------- K2: depthwise 3x3 conv + bias + SiLU -> u (b,d,l) ----------
__global__ __launch_bounds__(256) void k2_conv(
    const float* __restrict__ xc, const float* __restrict__ cw,
    const float* __restrict__ cb, float* __restrict__ u)
{
    __shared__ float pl[1024];
    const int bd = blockIdx.x;
    const int t  = threadIdx.x;
    const int d  = bd & 63;
    reinterpret_cast<float4*>(pl)[t] =
        reinterpret_cast<const float4*>(xc + (size_t)bd * 1024)[t];
    float w[9];
#pragma unroll
    for (int i = 0; i < 9; ++i) w[i] = cw[d * 9 + i];
    const float bias = cb[d];
    __syncthreads();
    float o[4];
#pragma unroll
    for (int i = 0; i < 4; ++i) {
        const int p  = t * 4 + i;
        const int py = p >> 5, px = p & 31;
        float s = 0.f;
#pragma unroll
        for (int ky = 0; ky < 3; ++ky) {
            const int iy = py + ky - 1;
            if (iy < 0 || iy > 31) continue;
#pragma unroll
            for (int kx = 0; kx < 3; ++kx) {
                const int ix = px + kx - 1;
                if (ix < 0 || ix > 31) continue;
                s = fmaf(pl[iy * 32 + ix], w[ky * 3 + kx], s);
            }
        }
        s += bias;
        o[i] = s / (1.f + __expf(-s));
    }
    reinterpret_cast<float4*>(u + (size_t)bd * 1024)[t] = make_float4(o[0], o[1], o[2], o[3]);
}

// ---------------- K3: x-proj (40 ch) + dt-proj + softplus --------------------
// 1024 blocks, one per 32-pixel strip. LDS-staged u tile + weights.
__global__ __launch_bounds__(256) void k3_xproj(
    const float* __restrict__ u, const float* __restrict__ xpw,
    const float* __restrict__ dtw_g, const float* __restrict__ dtb,
    float* __restrict__ delta, float* __restrict__ Bsp, float* __restrict__ Csp)
{
    __shared__ float ut[64][33];   // [d][pix]
    __shared__ float xd[40][33];   // [ch][pix]
    __shared__ float xw[64 * 40];  // [d][ch] transposed weights
    __shared__ float dwv[512];     // [d][r]
    const int t   = threadIdx.x;
    const int blk = blockIdx.x;          // 1024
    const int b   = blk >> 5;
    const int l0  = (blk & 31) * 32;

    for (int i = t; i < 2560; i += 256) {
        const int dd = i / 40, c = i - dd * 40;
        xw[i] = xpw[(size_t)c * 64 + dd];
    }
    for (int i = t; i < 512; i += 256) dwv[i] = dtw_g[i];

    {
        const int dd = t >> 2;           // 0..63
        const int lq = (t & 3) * 8;      // 0,8,16,24
        const float* up = u + ((size_t)b * 64 + dd) * 1024 + l0 + lq;
        const float4 v0 = *reinterpret_cast<const float4*>(up);
        const float4 v1 = *reinterpret_cast<const float4*>(up + 4);
        ut[dd][lq + 0] = v0.x; ut[dd][lq + 1] = v0.y;
        ut[dd][lq + 2] = v0.z; ut[dd][lq + 3] = v0.w;
        ut[dd][lq + 4] = v1.x; ut[dd][lq + 5] = v1.y;
        ut[dd][lq + 6] = v1.z; ut[dd][lq + 7] = v1.w;
    }
    __syncthreads();

    {
        const int pix = t & 31, cg = t >> 5;
        const int c0 = cg * 5;
        float a0 = 0.f, a1 = 0.f, a2 = 0.f, a3 = 0.f, a4 = 0.f;
#pragma unroll 8
        for (int dd = 0; dd < 64; ++dd) {
            const float uv = ut[dd][pix];
            const float* row = &xw[dd * 40 + c0];
            a0 = fmaf(uv, row[0], a0);
            a1 = fmaf(uv, row[1], a1);
            a2 = fmaf(uv, row[2], a2);
            a3 = fmaf(uv, row[3], a3);
            a4 = fmaf(uv, row[4], a4);
        }
        xd[c0 + 0][pix] = a0; xd[c0 + 1][pix] = a1; xd[c0 + 2][pix] = a2;
        xd[c0 + 3][pix] = a3; xd[c0 + 4][pix] = a4;
    }
    __syncthreads();

    // Bs/Cs stores: thread = (pix, nn = t>>5 in [0,8))
    {
        const int pix = t & 31, nn = t >> 5;
        float* bp = Bsp + (size_t)b * 16384 + l0 + pix;
        float* cp = Csp + (size_t)b * 16384 + l0 + pix;
        bp[(size_t)nn * 1024]       = xd[8 + nn][pix];
        bp[(size_t)(nn + 8) * 1024] = xd[16 + nn][pix];
        cp[(size_t)nn * 1024]       = xd[24 + nn][pix];
        cp[(size_t)(nn + 8) * 1024] = xd[32 + nn][pix];
    }
    // delta: thread = (pix, d-block of 8)
    {
        const int pix = t & 31;
        const int d0  = (t >> 5) * 8;
        float dts[8];
#pragma unroll
        for (int r = 0; r < 8; ++r) dts[r] = xd[r][pix];
        float* dp = delta + (size_t)b * 65536 + l0 + pix;
#pragma unroll
        for (int k = 0; k < 8; ++k) {
            const int dd = d0 + k;
            const float* r8 = &dwv[dd * 8];
            float s = dtb[dd];
            s = fmaf(dts[0], r8[0], s); s = fmaf(dts[1], r8[1], s);
            s = fmaf(dts[2], r8[2], s); s = fmaf(dts[3], r8[3], s);
            s = fmaf(dts[4], r8[4], s); s = fmaf(dts[5], r8[5], s);
            s = fmaf(dts[6], r8[6], s); s = fmaf(dts[7], r8[7], s);
            const float sp = fmaxf(s, 0.f) + log1pf(__expf(-fabsf(s)));
            dp[(size_t)dd * 1024] = sp;
        }
    }
}

// ---------------- K4: timestep-major chunked scan (block per (b,d)) ----------
// v4: B-row register cache. All 16 B-float4s are batch-loaded up-front
// (64 independent loads in flight) and reused in phase C -> B is read from
// L2 ONCE per block (was twice), and phase C's only loads are the 16
// independent C4s. L2 traffic 425 -> 294 MB, much higher MLP.
__global__ __launch_bounds__(256) void k4_scan(
    const float* __restrict__ delta, const float* __restrict__ u,
    const float* __restrict__ Bsp, const float* __restrict__ Csp,
    const float* __restrict__ A_logs, const float* __restrict__ Ds,
    float* __restrict__ y)
{
    __shared__ float Ps[256][17];
    __shared__ float qs[256][17];
    __shared__ float Sp[16][17];
    __shared__ float Sq[16][17];
    const int t = threadIdx.x;
    const int pair = blockIdx.x;    // b*64 + d
    const int b = pair >> 6, d = pair & 63;

    const float4 d4 = *reinterpret_cast<const float4*>(delta + (size_t)pair * 1024 + t * 4);
    const float4 u4 = *reinterpret_cast<const float4*>(u     + (size_t)pair * 1024 + t * 4);
    const float du0 = d4.x * u4.x, du1 = d4.y * u4.y;
    const float du2 = d4.z * u4.z, du3 = d4.w * u4.w;

    const float* Bb = Bsp + (size_t)b * 16384 + t * 4;
    const float* Cb = Csp + (size_t)b * 16384 + t * 4;

    // batched B load: 16 independent float4 loads -> register cache
    float Bc[64];
#pragma unroll
    for (int n = 0; n < 16; ++n)
        *reinterpret_cast<float4*>(&Bc[4 * n]) =
            *reinterpret_cast<const float4*>(Bb + (size_t)n * 1024);

    float A[16];
#pragma unroll
    for (int n = 0; n < 16; ++n) A[n] = -__expf(A_logs[d * 16 + n]);

    // ---- phase A: per-state 4-step affine reduce (no loads in loop) ----
#pragma unroll
    for (int n = 0; n < 16; ++n) {
        float a, P, q;
        a = __expf(d4.x * A[n]); P = a;   q = du0 * Bc[4*n+0];
        a = __expf(d4.y * A[n]); P *= a;  q = fmaf(a, q, du1 * Bc[4*n+1]);
        a = __expf(d4.z * A[n]); P *= a;  q = fmaf(a, q, du2 * Bc[4*n+2]);
        a = __expf(d4.w * A[n]); P *= a;  q = fmaf(a, q, du3 * Bc[4*n+3]);
        Ps[t][n] = P; qs[t][n] = q;
    }
    __syncthreads();

    // ---- phase B: scan over 256 chunks (16 segments x 16 chunks) ----
    const int n = t >> 4, g = t & 15;
    float rp[16], rq[16];
    {
        float Pseg = 1.f, qseg = 0.f;
#pragma unroll
        for (int i = 0; i < 16; ++i) {
            const int c = g * 16 + i;
            rp[i] = Ps[c][n]; rq[i] = qs[c][n];
            qseg = fmaf(rp[i], qseg, rq[i]);
            Pseg *= rp[i];
        }
        Sp[g][n] = Pseg; Sq[g][n] = qseg;
    }
    __syncthreads();
    if (t < 16) {
        float h = 0.f;
#pragma unroll
        for (int s = 0; s < 16; ++s) {
            const float Pv = Sp[s][t], qv = Sq[s][t];
            Sp[s][t] = h;
            h = fmaf(Pv, h, qv);
        }
    }
    __syncthreads();
    {
        float h = Sp[g][n];
#pragma unroll
        for (int i = 0; i < 16; ++i) {
            const int c = g * 16 + i;
            qs[c][n] = h;
            h = fmaf(rp[i], h, rq[i]);
        }
    }
    __syncthreads();

    // ---- phase C: replay with cached B; only C4 loads (independent) ----
    const float Dval = Ds[d];
    float y0 = Dval * u4.x, y1 = Dval * u4.y, y2 = Dval * u4.z, y3 = Dval * u4.w;
#pragma unroll
    for (int nn = 0; nn < 16; ++nn) {
        const float4 C4 = *reinterpret_cast<const float4*>(Cb + (size_t)nn * 1024);
        float h = qs[t][nn];
        float a;
        a = __expf(d4.x * A[nn]); h = fmaf(a, h, du0 * Bc[4*nn+0]); y0 = fmaf(h, C4.x, y0);
        a = __expf(d4.y * A[nn]); h = fmaf(a, h, du1 * Bc[4*nn+1]); y1 = fmaf(h, C4.y, y1);
        a = __expf(d4.z * A[nn]); h = fmaf(a, h, du2 * Bc[4*nn+2]); y2 = fmaf(h, C4.z, y2);
        a = __expf(d4.w * A[nn]); h = fmaf(a, h, du3 * Bc[4*nn+3]); y3 = fmaf(h, C4.w, y3);
    }
    *reinterpret_cast<float4*>(y + (size_t)pair * 1024 + t * 4) =
        make_float4(y0, y1, y2, y3);
}

// ---------------- K5: LayerNorm + silu(z) gate + out GEMM --------------------
__global__ __launch_bounds__(256) void k5_out(
    const float* __restrict__ y, const float* __restrict__ z,
    const float* __restrict__ ln_g, const float* __restrict__ ln_b,
    const float* __restrict__ w_out, float* __restrict__ out)
{
    __shared__ float yn[64 * 68];   // [l_local][d] stride 68
    __shared__ float wo[64 * 132];  // [d][c] pad 132
    const int t  = threadIdx.x;
    const int p0 = blockIdx.x * 64;
    const int b  = p0 >> 10, l0 = p0 & 1023;

    for (int i = t; i < 8192; i += 256) {
        const int c = i >> 6, dd = i & 63;
        wo[dd * 132 + c] = w_out[i];
    }

    {
        const int d = t >> 2;
        const float* yrow = y + ((size_t)b * 64 + d) * 1024 + l0;
#pragma unroll
        for (int k = 0; k < 4; ++k) {
            const int c4 = ((t & 3) + k * 4) * 4;
            const float4 v = *reinterpret_cast<const float4*>(&yrow[c4]);
            yn[(c4 + 0) * 68 + d] = v.x;
            yn[(c4 + 1) * 68 + d] = v.y;
            yn[(c4 + 2) * 68 + d] = v.z;
            yn[(c4 + 3) * 68 + d] = v.w;
        }
    }
    __syncthreads();

    const int lane = t & 63, wv = t >> 6;
    const float g = ln_g[lane], bbv = ln_b[lane];
#pragma unroll 1
    for (int i = 0; i < 16; ++i) {
        const int pl = wv * 16 + i;
        const size_t p = (size_t)p0 + pl;
        const float v  = yn[pl * 68 + lane];
        const float zv = z[p * 64 + lane];
        float s1 = v, s2 = v * v;
#pragma unroll
        for (int m = 1; m < 64; m <<= 1) {
            s1 += __shfl_xor(s1, m);
            s2 += __shfl_xor(s2, m);
        }
        const float mu   = s1 * (1.f / 64.f);
        const float var  = s2 * (1.f / 64.f) - mu * mu;
        const float rstd = rsqrtf(var + 1e-5f);
        const float sz   = zv / (1.f + __expf(-zv));
        yn[pl * 68 + lane] = ((v - mu) * rstd * g + bbv) * sz;
    }
    __syncthreads();

    const int tx = t & 31, ty = t >> 5;
    float acc[8][4];
#pragma unroll
    for (int i = 0; i < 8; ++i)
#pragma unroll
        for (int j = 0; j < 4; ++j) acc[i][j] = 0.f;

    for (int dd = 0; dd < 64; ++dd) {
        const float4 w4 = *reinterpret_cast<const float4*>(&wo[dd * 132 + (tx << 2)]);
#pragma unroll
        for (int i = 0; i < 8; ++i) {
            const float a = yn[(ty * 8 + i) * 68 + dd];
            acc[i][0] = fmaf(a, w4.x, acc[i][0]);
            acc[i][1] = fmaf(a, w4.y, acc[i][1]);
            acc[i][2] = fmaf(a, w4.z, acc[i][2]);
            acc[i][3] = fmaf(a, w4.w, acc[i][3]);
        }
    }
#pragma unroll
    for (int i = 0; i < 8; ++i) {
        const size_t p = (size_t)p0 + ty * 8 + i;
        *reinterpret_cast<float4*>(&out[p * 128 + (tx << 2)]) =
            make_float4(acc[i][0], acc[i][1], acc[i][2], acc[i][3]);
    }
}

extern "C" void kernel_launch(void* const* d_in, const int* in_sizes, int n_in,
                              void* d_out, int out_size, void* d_ws, size_t ws_size,
                              hipStream_t stream)
{
    const float* x        = (const float*)d_in[0];
    const float* w_in     = (const float*)d_in[1];
    const float* conv_w   = (const float*)d_in[2];
    const float* conv_b   = (const float*)d_in[3];
    const float* xproj_w  = (const float*)d_in[4];
    const float* dtproj_w = (const float*)d_in[5];
    const float* dtproj_b = (const float*)d_in[6];
    const float* A_logs   = (const float*)d_in[7];
    const float* Ds       = (const float*)d_in[8];
    const float* ln_g     = (const float*)d_in[9];
    const float* ln_b     = (const float*)d_in[10];
    const float* w_out    = (const float*)d_in[11];
    float* out = (float*)d_out;
    float* ws  = (float*)d_ws;

    const size_t M  = (size_t)2097152;  // 32*64*1024
    float* xc    = ws;                  // 8 MB
    float* z     = ws + M;              // 8 MB
    float* u     = ws + 2 * M;          // 8 MB
    float* delta = ws + 3 * M;          // 8 MB
    float* y     = ws + 4 * M;          // 8 MB  (b,d,l)
    float* Bsp   = ws + 5 * M;          // 2 MB
    float* Csp   = Bsp + 524288;        // 2 MB

    k1_gemm_in<<<512, 256, 0, stream>>>(x, w_in, xc, z);
    k2_conv<<<2048, 256, 0, stream>>>(xc, conv_w, conv_b, u);
    k3_xproj<<<1024, 256, 0, stream>>>(u, xproj_w, dtproj_w, dtproj_b, delta, Bsp, Csp);
    k4_scan<<<2048, 256, 0, stream>>>(delta, u, Bsp, Csp, A_logs, Ds, y);
    k5_out<<<512, 256, 0, stream>>>(y, z, ln_g, ln_b, w_out, out);
}